// Round 6
// baseline (189.740 us; speedup 1.0000x reference)
//
#include <hip/hip_runtime.h>
#include <hip/hip_bf16.h>
#include <cstdint>
#include <cstddef>

// Problem constants
#define BB 8192
#define UU 512
#define KPACK 1024   // D + U
#define NPACK 2048   // 4*U

using frag16 = __attribute__((ext_vector_type(8))) short;   // 8 bf16 = 16 B (4 VGPRs)
using f32x4  = __attribute__((ext_vector_type(4))) float;

// Epilogue transcendentals via single-instruction v_rcp_f32 (verified R5 win).
__device__ inline float fast_sigmoid(float x) {
  float e = __expf(-x);
  return __builtin_amdgcn_rcpf(1.0f + e);
}
__device__ inline float fast_tanh(float x) {
  float e = __expf(-2.0f * x);
  return fmaf(2.0f, __builtin_amdgcn_rcpf(1.0f + e), -1.0f);
}

// packed RNE f32x2 -> bf16x2 (v_cvt_pk_bf16_f32 on gfx950 via hip_bf16.h)
__device__ inline unsigned cvt2(float lo, float hi) {
  __hip_bfloat162 b = __float22bfloat162_rn(float2{lo, hi});
  union { __hip_bfloat162 b; unsigned u; } v; v.b = b;
  return v.u;
}

// ---- merged pack kernel (UNCHANGED from verified version) ----
__global__ __launch_bounds__(256) void pack_kernel(const float* __restrict__ x,
                                                   const float* __restrict__ h,
                                                   const float* __restrict__ W,
                                                   const float* __restrict__ R,
                                                   short* __restrict__ Xp,
                                                   short* __restrict__ Bt) {
  if (blockIdx.x < 4096) {
    int idx = blockIdx.x * 256 + threadIdx.x;
    int row = idx >> 7;             // /128 chunks per row
    int k8  = (idx & 127) << 3;     // 0..1016  (wave-uniform x/h split)
    const float* src = (k8 < 512) ? (x + (size_t)row * 512 + k8)
                                  : (h + (size_t)row * 512 + (k8 - 512));
    float4 a = *(const float4*)(src);
    float4 b = *(const float4*)(src + 4);
    uint4 o;
    o.x = cvt2(a.x, a.y);
    o.y = cvt2(a.z, a.w);
    o.z = cvt2(b.x, b.y);
    o.w = cvt2(b.z, b.w);
    *(uint4*)(Xp + ((size_t)idx << 3)) = o;
  } else {
    __shared__ float tile[64][65];   // +1 pad: conflict-free transpose
    int b2 = blockIdx.x - 4096;      // 512 blocks: 32 n-tiles x 16 k-tiles
    int nb = (b2 & 31) * 64;
    int kb = (b2 >> 5) * 64;
    int t  = threadIdx.x;
#pragma unroll
    for (int rep = 0; rep < 16; ++rep) {
      int kr = rep * 4 + (t >> 6);
      int c  = t & 63;
      int kg = kb + kr;
      const float* s = (kg < 512) ? (W + (size_t)kg * 2048) : (R + (size_t)(kg - 512) * 2048);
      tile[c][kr] = s[nb + c];
    }
    __syncthreads();
#pragma unroll
    for (int rep = 0; rep < 4; ++rep) {
      int nn = rep * 16 + (t >> 4);
      int k4 = (t & 15) << 2;
      uint2 o;
      o.x = cvt2(tile[nn][k4 + 0], tile[nn][k4 + 1]);
      o.y = cvt2(tile[nn][k4 + 2], tile[nn][k4 + 3]);
      *(uint2*)(Bt + (size_t)(nb + nn) * 1024 + kb + k4) = o;
    }
  }
}

// ---- fused GEMM + LSTM pointwise: R0 tile + 2-phase recipe + B-direct ----
// Tile/waves/swizzle/epilogue identical to the verified 50.4us R0 config
// (BM=128 x 32u x 4g, 4 waves, wave-tile 64x64, acc[4][4]).
// Two coupled changes:
//  (1) B operand loaded DIRECTLY from global Bt (L2-resident, 4 MB) instead of
//      LDS staging. Address (j*512+u)*1024 + kt*64 + s*32 + q*8 delivers
//      byte-identical values to the old swizzled-LDS path (unswizzle algebra:
//      slot (4s+q)^mx at row n holds chunk 4s+q since mx == n&7).
//  (2) A staging double-buffered at BK=64 (2 x 16 KB = 32 KB LDS, still
//      4 blocks/CU) with the T3 minimum-2-phase schedule: per step
//      {8 B-loads -> STAGE(t+1) -> ds_read+MFMA -> vmcnt(0) -> raw s_barrier}.
//      The vmcnt(0) publish sits AFTER the MFMA cluster, so tile-(t+1) loads
//      get the whole compute phase to land (R0 drained them immediately after
//      issue -> full latency exposed 16x). B-loads are issued BEFORE staging,
//      so the compiler's exact wait for B is a counted vmcnt(4) that leaves
//      staging in flight through compute. Barriers: 16 (was 32).
// Cross-wave publish: each wave drains its OWN staging (vmcnt is per-wave)
// before the shared barrier -- the only sound publish point for gload_lds.
// MFMA accumulation order unchanged -> numerics bit-identical.
__global__ __launch_bounds__(256, 4) void lstm_mfma_kernel(
    const short* __restrict__ A,     // bf16 [8192][1024]
    const short* __restrict__ Bt,    // bf16 [2048][1024], row n = z column
    const float* __restrict__ bias,  // [2048]
    const float* __restrict__ cprev, // [8192][512]
    float* __restrict__ out)         // h, h, c concatenated
{
  __shared__ short lds_a[2 * 8192];   // 2 x [128][64] bf16 = 32 KB

  const int tid  = threadIdx.x;
  const int lane = tid & 63;
  const int wave = tid >> 6;
  const int wm = wave & 1, wn = wave >> 1;
  const int bm = blockIdx.x;   // 64
  const int bn = blockIdx.y;   // 16

  // A staging decomposition: 8 lanes per 128B row, xor-swizzle k-chunks
  // (identical involution to verified version).
  const int r8  = lane >> 3;
  const int kg  = lane & 7;
  const int kgx = kg ^ r8;

  const short* ga[4];
  int ls_off[4];
#pragma unroll
  for (int t = 0; t < 4; ++t) {
    int rowl = wave * 32 + t * 8 + r8;   // local row 0..127
    ga[t] = A + (size_t)(bm * 128 + rowl) * 1024 + kgx * 8;
    ls_off[t] = (wave * 32 + t * 8) * 64;
  }

  const int q   = lane >> 4;
  const int c16 = lane & 15;
  const int mx  = c16 & 7;

  // B direct-from-global bases: unit u = bn*32 + wn*16 + c16, gate j.
  const int u = bn * 32 + wn * 16 + c16;
  const short* Bp[4];
#pragma unroll
  for (int j = 0; j < 4; ++j)
    Bp[j] = Bt + (size_t)(j * 512 + u) * 1024 + q * 8;

  // 4 global_load_lds (A only) for K-step kt into buffer bi
  auto STAGE = [&](int kt, int bi) {
    const int k0 = kt * 64;
    short* base = lds_a + bi * 8192;
#pragma unroll
    for (int t = 0; t < 4; ++t)
      __builtin_amdgcn_global_load_lds(
          (const __attribute__((address_space(1))) void*)(ga[t] + k0),
          (__attribute__((address_space(3))) void*)(base + ls_off[t]), 16, 0, 0);
  };

  f32x4 acc[4][4];
#pragma unroll
  for (int i = 0; i < 4; ++i)
#pragma unroll
    for (int j = 0; j < 4; ++j)
      acc[i][j] = f32x4{0.f, 0.f, 0.f, 0.f};

  // prologue: stage tile 0, publish
  STAGE(0, 0);
  asm volatile("s_waitcnt vmcnt(0)" ::: "memory");
  __builtin_amdgcn_s_barrier();

  for (int kt = 0; kt < 16; ++kt) {
    const short* la = lds_a + (kt & 1) * 8192;

    // 8 B-fragment global loads first (oldest VMEM of this step)
    frag16 bfv[2][4];
#pragma unroll
    for (int s = 0; s < 2; ++s)
#pragma unroll
      for (int j = 0; j < 4; ++j)
        bfv[s][j] = *(const frag16*)(Bp[j] + kt * 64 + s * 32);

    // then issue next tile's staging (newest -> stays in flight thru compute)
    if (kt < 15) STAGE(kt + 1, (kt + 1) & 1);

#pragma unroll
    for (int s = 0; s < 2; ++s) {
      const int kch = (((s << 2) + q) ^ mx) << 3;
      frag16 af[4];
#pragma unroll
      for (int i = 0; i < 4; ++i)
        af[i] = *(const frag16*)(la + (wm * 64 + i * 16 + c16) * 64 + kch);
#pragma unroll
      for (int i = 0; i < 4; ++i)
#pragma unroll
        for (int j = 0; j < 4; ++j)
          acc[i][j] = __builtin_amdgcn_mfma_f32_16x16x32_bf16(af[i], bfv[s][j], acc[i][j], 0, 0, 0);
    }

    // publish this step's staging (covered by the compute above), then barrier
    asm volatile("s_waitcnt vmcnt(0)" ::: "memory");
    __builtin_amdgcn_s_barrier();
  }

  // epilogue: lane-local LSTM pointwise (unchanged, R5 rcp version).
  const float b0 = bias[u];
  const float b1 = bias[512 + u];
  const float b2 = bias[1024 + u];
  const float b3 = bias[1536 + u];
  float* outh0 = out;
  float* outh1 = out + (size_t)BB * UU;
  float* outc  = out + (size_t)2 * BB * UU;

#pragma unroll
  for (int i = 0; i < 4; ++i) {
    int row0 = bm * 128 + wm * 64 + i * 16 + q * 4;
#pragma unroll
    for (int r = 0; r < 4; ++r) {
      size_t off = (size_t)(row0 + r) * UU + u;
      float z0 = acc[i][0][r] + b0;
      float z1 = acc[i][1][r] + b1;
      float z2 = acc[i][2][r] + b2;
      float z3 = acc[i][3][r] + b3;
      float ig = fast_sigmoid(z0);
      float fg = fast_sigmoid(z1);
      float gg = fast_tanh(z2);
      float og = fast_sigmoid(z3);
      float cp = cprev[off];
      float cc = fg * cp + ig * gg;
      float hh = og * fast_tanh(cc);
      outh0[off] = hh;
      outh1[off] = hh;
      outc[off]  = cc;
    }
  }
}

extern "C" void kernel_launch(void* const* d_in, const int* in_sizes, int n_in,
                              void* d_out, int out_size, void* d_ws, size_t ws_size,
                              hipStream_t stream) {
  const float* x  = (const float*)d_in[0];
  const float* h  = (const float*)d_in[1];
  const float* c  = (const float*)d_in[2];
  const float* W  = (const float*)d_in[3];
  const float* R  = (const float*)d_in[4];
  const float* b  = (const float*)d_in[5];
  float* out = (float*)d_out;

  short* Xp = (short*)d_ws;                        // 16 MB bf16 [8192][1024]
  short* Bt = Xp + (size_t)BB * KPACK;             // 4 MB  bf16 [2048][1024]

  pack_kernel<<<4608, 256, 0, stream>>>(x, h, W, R, Xp, Bt);
  lstm_mfma_kernel<<<dim3(64, 16), 256, 0, stream>>>(Xp, Bt, b, c, out);
}

// Round 7
// 150.889 us; speedup vs baseline: 1.2575x; 1.2575x over previous
//
#include <hip/hip_runtime.h>
#include <hip/hip_bf16.h>
#include <cstdint>
#include <cstddef>

// Problem constants
#define BB 8192
#define UU 512
#define KPACK 1024   // D + U
#define NPACK 2048   // 4*U

using frag16 = __attribute__((ext_vector_type(8))) short;   // 8 bf16 = 16 B (4 VGPRs)
using f32x4  = __attribute__((ext_vector_type(4))) float;
using f32x16 = __attribute__((ext_vector_type(16))) float;

// Epilogue transcendentals via single-instruction v_rcp_f32 (verified R5 win).
__device__ inline float fast_sigmoid(float x) {
  float e = __expf(-x);
  return __builtin_amdgcn_rcpf(1.0f + e);
}
__device__ inline float fast_tanh(float x) {
  float e = __expf(-2.0f * x);
  return fmaf(2.0f, __builtin_amdgcn_rcpf(1.0f + e), -1.0f);
}

// packed RNE f32x2 -> bf16x2 (v_cvt_pk_bf16_f32 on gfx950 via hip_bf16.h)
__device__ inline unsigned cvt2(float lo, float hi) {
  __hip_bfloat162 b = __float22bfloat162_rn(float2{lo, hi});
  union { __hip_bfloat162 b; unsigned u; } v; v.b = b;
  return v.u;
}

// ---- merged pack kernel (UNCHANGED from verified version) ----
__global__ __launch_bounds__(256) void pack_kernel(const float* __restrict__ x,
                                                   const float* __restrict__ h,
                                                   const float* __restrict__ W,
                                                   const float* __restrict__ R,
                                                   short* __restrict__ Xp,
                                                   short* __restrict__ Bt) {
  if (blockIdx.x < 4096) {
    int idx = blockIdx.x * 256 + threadIdx.x;
    int row = idx >> 7;             // /128 chunks per row
    int k8  = (idx & 127) << 3;     // 0..1016  (wave-uniform x/h split)
    const float* src = (k8 < 512) ? (x + (size_t)row * 512 + k8)
                                  : (h + (size_t)row * 512 + (k8 - 512));
    float4 a = *(const float4*)(src);
    float4 b = *(const float4*)(src + 4);
    uint4 o;
    o.x = cvt2(a.x, a.y);
    o.y = cvt2(a.z, a.w);
    o.z = cvt2(b.x, b.y);
    o.w = cvt2(b.z, b.w);
    *(uint4*)(Xp + ((size_t)idx << 3)) = o;
  } else {
    __shared__ float tile[64][65];   // +1 pad: conflict-free transpose
    int b2 = blockIdx.x - 4096;      // 512 blocks: 32 n-tiles x 16 k-tiles
    int nb = (b2 & 31) * 64;
    int kb = (b2 >> 5) * 64;
    int t  = threadIdx.x;
#pragma unroll
    for (int rep = 0; rep < 16; ++rep) {
      int kr = rep * 4 + (t >> 6);
      int c  = t & 63;
      int kg = kb + kr;
      const float* s = (kg < 512) ? (W + (size_t)kg * 2048) : (R + (size_t)(kg - 512) * 2048);
      tile[c][kr] = s[nb + c];
    }
    __syncthreads();
#pragma unroll
    for (int rep = 0; rep < 4; ++rep) {
      int nn = rep * 16 + (t >> 4);
      int k4 = (t & 15) << 2;
      uint2 o;
      o.x = cvt2(tile[nn][k4 + 0], tile[nn][k4 + 1]);
      o.y = cvt2(tile[nn][k4 + 2], tile[nn][k4 + 3]);
      *(uint2*)(Bt + (size_t)(nb + nn) * 1024 + kb + k4) = o;
    }
  }
}

// ---- fused GEMM + LSTM pointwise: R5 skeleton, 32x32x16 MFMA ----
// Identical to the verified R5 config (BM=128 x 128 cols, 4 waves, 32 KB LDS,
// single-buffered stage->sync->compute->sync loop, XOR chunk swizzle, rcp
// epilogue) EXCEPT the MFMA shape: 32x32x16 (2382 TF ceiling vs 2075, and
// HALF the MFMA instruction count inside the lockstep compute phase).
//  - wave decomposition: wave w owns row band w*32..w*32+31; each wave
//    computes ALL 128 N cols as 4 fragments j = gate j of 32 units.
//  - epilogue lane-locality preserved: C/D col = lane&31 = unit,
//    fragment j = gate; row = (reg&3) + 8*(reg>>2) + 4*(lane>>5)
//    (HW-verified 32x32 mapping, m74/m101).
//  - B staging row-map: tile row n -> gate = n>>5, u = bn*32 + (n&31).
//  - read slot = (2*s4 | lane>>5) ^ (lane&7): 8 lanes per 4-bank slot group
//    = 2 lanes/bank = conflict-free (same class as verified reads).
// Staging (gload_lds pattern + LDS image) is byte-identical to R5.
__global__ __launch_bounds__(256, 4) void lstm_mfma_kernel(
    const short* __restrict__ A,     // bf16 [8192][1024]
    const short* __restrict__ Bt,    // bf16 [2048][1024], row n = z column
    const float* __restrict__ bias,  // [2048]
    const float* __restrict__ cprev, // [8192][512]
    float* __restrict__ out)         // h, h, c concatenated
{
  __shared__ short lds_a[128 * 64];
  __shared__ short lds_b[128 * 64];

  const int tid  = threadIdx.x;
  const int lane = tid & 63;
  const int wave = tid >> 6;     // 0..3: row band wave*32..+31
  const int bm = blockIdx.x;     // 64
  const int bn = blockIdx.y;     // 16

  // staging decomposition: 8 lanes per 128B row, xor-swizzle k-chunks
  // (identical involution to verified version: LDS slot sl holds chunk
  //  sl ^ (row&7)).
  const int r8  = lane >> 3;
  const int kg  = lane & 7;
  const int kgx = kg ^ r8;

  const short* ga[4];
  const short* gb[4];
  int ls_off[4];
#pragma unroll
  for (int t = 0; t < 4; ++t) {
    int rowl = wave * 32 + t * 8 + r8;   // local row 0..127
    ga[t] = A + (size_t)(bm * 128 + rowl) * 1024 + kgx * 8;
    int u_b  = bn * 32 + (rowl & 31);    // NEW map: 32-unit groups
    int gate = rowl >> 5;
    gb[t] = Bt + (size_t)(gate * 512 + u_b) * 1024 + kgx * 8;
    ls_off[t] = (wave * 32 + t * 8) * 64;
  }

  const int l31 = lane & 31;
  const int q2  = lane >> 5;   // k-group within fragment
  const int mx8 = lane & 7;    // == row&7 for all fragment reads below

  f32x16 acc[4];
#pragma unroll
  for (int j = 0; j < 4; ++j)
    acc[j] = (f32x16)(0.0f);

  for (int kt = 0; kt < 16; ++kt) {
    const int k0 = kt * 64;
#pragma unroll
    for (int t = 0; t < 4; ++t)
      __builtin_amdgcn_global_load_lds(
          (const __attribute__((address_space(1))) void*)(ga[t] + k0),
          (__attribute__((address_space(3))) void*)(lds_a + ls_off[t]), 16, 0, 0);
#pragma unroll
    for (int t = 0; t < 4; ++t)
      __builtin_amdgcn_global_load_lds(
          (const __attribute__((address_space(1))) void*)(gb[t] + k0),
          (__attribute__((address_space(3))) void*)(lds_b + ls_off[t]), 16, 0, 0);
    __syncthreads();   // compiler emits vmcnt(0) drain here
#pragma unroll
    for (int s4 = 0; s4 < 4; ++s4) {        // K=16 slices, ascending
      const int kch = (((s4 << 1) | q2) ^ mx8) << 3;   // swizzled 8-short chunk
      frag16 af = *(const frag16*)(lds_a + (wave * 32 + l31) * 64 + kch);
      frag16 bfv[4];
#pragma unroll
      for (int j = 0; j < 4; ++j)
        bfv[j] = *(const frag16*)(lds_b + (j * 32 + l31) * 64 + kch);
#pragma unroll
      for (int j = 0; j < 4; ++j)
        acc[j] = __builtin_amdgcn_mfma_f32_32x32x16_bf16(af, bfv[j], acc[j], 0, 0, 0);
    }
    __syncthreads();
  }

  // epilogue: lane-local LSTM pointwise. col = lane&31 -> unit, fragment j ->
  // gate. Row (32x32 C/D map): (reg&3) + 8*(reg>>2) + 4*q2.
  const int u = bn * 32 + l31;
  const float b0 = bias[u];
  const float b1 = bias[512 + u];
  const float b2 = bias[1024 + u];
  const float b3 = bias[1536 + u];
  float* outh0 = out;
  float* outh1 = out + (size_t)BB * UU;
  float* outc  = out + (size_t)2 * BB * UU;

#pragma unroll
  for (int g = 0; g < 4; ++g) {
#pragma unroll
    for (int rr = 0; rr < 4; ++rr) {
      const int r16 = g * 4 + rr;
      const int row = bm * 128 + wave * 32 + rr + 8 * g + 4 * q2;
      size_t off = (size_t)row * UU + u;
      float z0 = acc[0][r16] + b0;
      float z1 = acc[1][r16] + b1;
      float z2 = acc[2][r16] + b2;
      float z3 = acc[3][r16] + b3;
      float ig = fast_sigmoid(z0);
      float fg = fast_sigmoid(z1);
      float gg = fast_tanh(z2);
      float og = fast_sigmoid(z3);
      float cp = cprev[off];
      float cc = fg * cp + ig * gg;
      float hh = og * fast_tanh(cc);
      outh0[off] = hh;
      outh1[off] = hh;
      outc[off]  = cc;
    }
  }
}

extern "C" void kernel_launch(void* const* d_in, const int* in_sizes, int n_in,
                              void* d_out, int out_size, void* d_ws, size_t ws_size,
                              hipStream_t stream) {
  const float* x  = (const float*)d_in[0];
  const float* h  = (const float*)d_in[1];
  const float* c  = (const float*)d_in[2];
  const float* W  = (const float*)d_in[3];
  const float* R  = (const float*)d_in[4];
  const float* b  = (const float*)d_in[5];
  float* out = (float*)d_out;

  short* Xp = (short*)d_ws;                        // 16 MB bf16 [8192][1024]
  short* Bt = Xp + (size_t)BB * KPACK;             // 4 MB  bf16 [2048][1024]

  pack_kernel<<<4608, 256, 0, stream>>>(x, h, W, R, Xp, Bt);
  lstm_mfma_kernel<<<dim3(64, 16), 256, 0, stream>>>(Xp, Bt, b, c, out);
}